// Round 3
// baseline (348.277 us; speedup 1.0000x reference)
//
#include <hip/hip_runtime.h>
#include <hip/hip_cooperative_groups.h>
#include <hip/hip_bf16.h>
#include <math.h>

#define SEQ   2048
#define H     1024
#define VOCAB 32000
#define GRID  512
#define NTHR  256

namespace cg = cooperative_groups;

__device__ inline float4 ld4(const float* p) { return *reinterpret_cast<const float4*>(p); }
__device__ inline float dot4(float4 a, float4 b) { return a.x*b.x + a.y*b.y + a.z*b.z + a.w*b.w; }
__device__ inline float sigmoidf(float x) { return 1.f / (1.f + expf(-x)); }

__device__ inline void omerge(float& m, float& s, float m2, float s2) {
    if (m2 > m) { s = s * __expf(m - m2) + s2; m = m2; }
    else if (s2 != 0.f) { s += s2 * __expf(m2 - m); }
}

__device__ inline float waveSum(float v) {
#pragma unroll
    for (int off = 32; off > 0; off >>= 1) v += __shfl_down(v, off, 64);
    return v;
}
__device__ inline float waveMax(float v) {
#pragma unroll
    for (int off = 32; off > 0; off >>= 1) v = fmaxf(v, __shfl_down(v, off, 64));
    return v;
}

// ======================= cooperative fused kernel ==========================

// all 256 threads return merged (M,S) over part[0..GRID-1] (GRID=512)
__device__ inline float2 reducePartials512(const float2* __restrict__ part, float2* s2buf) {
    const int t = threadIdx.x, wid = t >> 6, lane = t & 63;
    float2 a = part[t], b = part[t + 256];
    float m = a.x, s = a.y;
    omerge(m, s, b.x, b.y);
#pragma unroll
    for (int off = 32; off > 0; off >>= 1) {
        float m2 = __shfl_down(m, off, 64), ss = __shfl_down(s, off, 64);
        omerge(m, s, m2, ss);
    }
    __syncthreads();
    if (lane == 0) s2buf[wid] = make_float2(m, s);
    __syncthreads();
    float M = s2buf[0].x, S = s2buf[0].y;
#pragma unroll
    for (int q = 1; q < 4; ++q) omerge(M, S, s2buf[q].x, s2buf[q].y);
    return make_float2(M, S);
}

__global__ __launch_bounds__(NTHR, 2) void kfused(
        const float* __restrict__ emb,  const float* __restrict__ lctx,
        const float* __restrict__ h0,   const float* __restrict__ W_ih,
        const float* __restrict__ W_hh, const float* __restrict__ b_ih,
        const float* __restrict__ b_hh, const int* __restrict__ widx,
        const float* __restrict__ enc,  const float* __restrict__ Wa,
        const float* __restrict__ Wl,   const float* __restrict__ bl,
        float* __restrict__ ws, float* __restrict__ out) {
    cg::grid_group grid = cg::this_grid();
    const int bid = blockIdx.x, t = threadIdx.x;
    const int wid = t >> 6, lane = t & 63;
    const int gw = bid * 4 + wid;               // global wave id 0..2047

    // ws layout (floats) — total 39168 floats = 156672 B
    float*  vcat   = ws;                        // [2048] = h | ctx
    float*  h      = vcat;
    float*  ctx    = vcat + H;
    float*  u      = ws + 2048;                 // [1024]
    float*  energ  = ws + 3072;                 // [2048]
    float2* part_e = (float2*)(ws + 5120);      // [512]
    float2* part_l = (float2*)(ws + 6144);      // [512]
    float*  logits = ws + 7168;                 // [32000]

    __shared__ float  sh[64];
    __shared__ float  se[4];
    __shared__ float2 s2[4];

    // ============ P1: LSTM cell — one wave per output j (waves 0..1023) ====
    {
        if (bid == 0) for (int k = t; k < H; k += NTHR) u[k] = 0.f;
        if (bid == 1) for (int k = t; k < H; k += NTHR) ctx[k] = 0.f;

        if (gw < H) {
            const int j = gw;
            const int w = widx[0];              // int64 LE, value < 32000
            const float* embrow = emb + (size_t)w * H;
            const float* wi = W_ih + (size_t)j * (2 * H);
            const float* wg = W_ih + (size_t)(j + 2 * H) * (2 * H);
            const float* wo = W_ih + (size_t)(j + 3 * H) * (2 * H);
            const float* vi = W_hh + (size_t)j * H;
            const float* vg = W_hh + (size_t)(j + 2 * H) * H;
            const float* vo = W_hh + (size_t)(j + 3 * H) * H;
            float ai = 0.f, ag = 0.f, ao = 0.f;
#pragma unroll
            for (int s = 0; s < 4; ++s) {
                const int e = s * 256 + lane * 4;
                float4 xe = ld4(embrow + e), xc = ld4(lctx + e), xh = ld4(h0 + e);
                ai += dot4(ld4(wi + e), xe) + dot4(ld4(wi + H + e), xc) + dot4(ld4(vi + e), xh);
                ag += dot4(ld4(wg + e), xe) + dot4(ld4(wg + H + e), xc) + dot4(ld4(vg + e), xh);
                ao += dot4(ld4(wo + e), xe) + dot4(ld4(wo + H + e), xc) + dot4(ld4(vo + e), xh);
            }
            ai = waveSum(ai); ag = waveSum(ag); ao = waveSum(ao);
            if (lane == 0) {
                ai += b_ih[j] + b_hh[j];
                ag += b_ih[j + 2 * H] + b_hh[j + 2 * H];
                ao += b_ih[j + 3 * H] + b_hh[j + 3 * H];
                float c = sigmoidf(ai) * tanhf(ag);   // c0 == 0 -> f-gate dead
                h[j] = sigmoidf(ao) * tanhf(c);
            }
        }
    }
    grid.sync();  // ---- h, u=0, ctx=0 ----

    // ============ P2: u = Wa^T h (64 blocks, atomics, contention 16) =======
    if (bid < 64) {
        const int j0 = (bid >> 2) * 64, kb = bid & 3;
        if (t < 64) sh[t] = h[j0 + t];
        __syncthreads();
        const int k = kb * 256 + t;
        float acc = 0.f;
#pragma unroll 8
        for (int jj = 0; jj < 64; ++jj)
            acc += Wa[(size_t)(j0 + jj) * H + k] * sh[jj];
        atomicAdd(&u[k], acc);
    }
    grid.sync();  // ---- u ----

    // ============ P3: energies — one wave per row + block (m,s) partial ====
    {
        const float* er = enc + (size_t)gw * H;
        float e = 0.f;
#pragma unroll
        for (int s = 0; s < 4; ++s) {
            const int k = s * 256 + lane * 4;
            e += dot4(ld4(er + k), ld4(u + k));
        }
        e = waveSum(e);
        if (lane == 0) { energ[gw] = e; se[wid] = e; }
        __syncthreads();
        if (t == 0) {
            float m = fmaxf(fmaxf(se[0], se[1]), fmaxf(se[2], se[3]));
            float s = __expf(se[0] - m) + __expf(se[1] - m)
                    + __expf(se[2] - m) + __expf(se[3] - m);
            part_e[bid] = make_float2(m, s);
        }
    }
    grid.sync();  // ---- energ, part_e ----

    // ============ P4: context = softmax(energ) @ enc (128 blocks) ==========
    if (bid < 128) {
        float2 MS = reducePartials512(part_e, s2);
        const float M = MS.x, invS = 1.f / MS.y;
        const int j0 = (bid >> 2) * 64, kb = bid & 3;
        __syncthreads();
        if (t < 64) sh[t] = __expf(energ[j0 + t] - M) * invS;
        __syncthreads();
        const int k = kb * 256 + t;
        float acc = 0.f;
#pragma unroll 8
        for (int jj = 0; jj < 64; ++jj)
            acc += sh[jj] * enc[(size_t)(j0 + jj) * H + k];
        atomicAdd(&ctx[k], acc);
    }
    grid.sync();  // ---- ctx -> vcat ready ----

    // ===== P5: logits = Wl @ vcat + bl with fused online (max,sumexp) ======
    {
        float lm = -INFINITY, ls = 0.f;
#pragma unroll 1
        for (int it = 0; it < 16; ++it) {
            const int row = it * (GRID * 4) + gw;
            if (row < VOCAB) {
                const float* wr = Wl + (size_t)row * (2 * H);
                float acc = 0.f;
#pragma unroll
                for (int q = 0; q < 8; ++q) {
                    const int e = q * 256 + lane * 4;
                    acc += dot4(ld4(wr + e), ld4(vcat + e));
                }
                acc = waveSum(acc);
                if (lane == 0) {
                    float v = acc + bl[row];
                    logits[row] = v;
                    omerge(lm, ls, v, 1.f);
                }
            }
        }
        __syncthreads();
        if (lane == 0) s2[wid] = make_float2(lm, ls);
        __syncthreads();
        if (t == 0) {
            float M = s2[0].x, S = s2[0].y;
            for (int q = 1; q < 4; ++q) omerge(M, S, s2[q].x, s2[q].y);
            part_l[bid] = make_float2(M, S);
        }
    }
    grid.sync();  // ---- logits, part_l ----

    // ============ P6: out = logits - logsumexp =============================
    {
        float2 MS = reducePartials512(part_l, s2);
        const float lse = MS.x + logf(MS.y);
        for (int i = bid * NTHR + t; i < VOCAB; i += GRID * NTHR)
            out[i] = logits[i] - lse;
    }
}

// ======================= fallback path (round-1, proven) ===================

__global__ __launch_bounds__(256) void k_lstm(
        const float* __restrict__ emb, const float* __restrict__ lctx,
        const float* __restrict__ h0,  const float* __restrict__ W_ih,
        const float* __restrict__ W_hh, const float* __restrict__ b_ih,
        const float* __restrict__ b_hh, const int* __restrict__ widx,
        float* __restrict__ h_out, float* __restrict__ u_zero) {
    const int j = blockIdx.x, t = threadIdx.x;
    const int wid = t >> 6, lane = t & 63;
    if (j == 0) for (int k = t; k < H; k += 256) u_zero[k] = 0.f;
    const int w = widx[0];
    const float* embrow = emb + (size_t)w * H;
    const int ri = j, rg = j + 2 * H, ro = j + 3 * H;
    const float* wi_i = W_ih + (size_t)ri * (2 * H);
    const float* wi_g = W_ih + (size_t)rg * (2 * H);
    const float* wi_o = W_ih + (size_t)ro * (2 * H);
    const float* wh_i = W_hh + (size_t)ri * H;
    const float* wh_g = W_hh + (size_t)rg * H;
    const float* wh_o = W_hh + (size_t)ro * H;
    float ai = 0.f, ag = 0.f, ao = 0.f;
    { int e = t*4; float4 x = ld4(embrow+e);
      ai += dot4(ld4(wi_i+e),x); ag += dot4(ld4(wi_g+e),x); ao += dot4(ld4(wi_o+e),x); }
    { int e = t*4; float4 x = ld4(lctx+e);
      ai += dot4(ld4(wi_i+H+e),x); ag += dot4(ld4(wi_g+H+e),x); ao += dot4(ld4(wi_o+H+e),x); }
    { int e = t*4; float4 x = ld4(h0+e);
      ai += dot4(ld4(wh_i+e),x); ag += dot4(ld4(wh_g+e),x); ao += dot4(ld4(wh_o+e),x); }
    ai = waveSum(ai); ag = waveSum(ag); ao = waveSum(ao);
    __shared__ float lds[12];
    if (lane == 0) { lds[wid*3] = ai; lds[wid*3+1] = ag; lds[wid*3+2] = ao; }
    __syncthreads();
    if (t == 0) {
        float gi = 0.f, gg = 0.f, go = 0.f;
        for (int q = 0; q < 4; ++q) { gi += lds[q*3]; gg += lds[q*3+1]; go += lds[q*3+2]; }
        gi += b_ih[ri] + b_hh[ri];
        gg += b_ih[rg] + b_hh[rg];
        go += b_ih[ro] + b_hh[ro];
        float c = sigmoidf(gi) * tanhf(gg);
        h_out[j] = sigmoidf(go) * tanhf(c);
    }
}

__global__ __launch_bounds__(256) void k_wa(
        const float* __restrict__ Wa, const float* __restrict__ h,
        float* __restrict__ u) {
    const int k = blockIdx.x * 256 + threadIdx.x;
    const int j0 = blockIdx.y * 32;
    float acc = 0.f;
#pragma unroll 8
    for (int j = j0; j < j0 + 32; ++j) acc += Wa[(size_t)j * H + k] * h[j];
    atomicAdd(&u[k], acc);
}

__global__ __launch_bounds__(256) void k_energy(
        const float* __restrict__ enc, const float* __restrict__ u,
        float* __restrict__ energ) {
    const int wid = threadIdx.x >> 6, lane = threadIdx.x & 63;
    const int row = blockIdx.x * 4 + wid;
    const float* er = enc + (size_t)row * H;
    float acc = 0.f;
#pragma unroll
    for (int it = 0; it < 4; ++it) { int e = it*256 + lane*4; acc += dot4(ld4(er+e), ld4(u+e)); }
    acc = waveSum(acc);
    if (lane == 0) energ[row] = acc;
}

__global__ __launch_bounds__(1024) void k_softmax(
        const float* __restrict__ energ, float* __restrict__ attw,
        float* __restrict__ ctx_zero) {
    const int t = threadIdx.x, wid = t >> 6, lane = t & 63;
    __shared__ float red[16];
    ctx_zero[t] = 0.f;
    float e0 = energ[t], e1 = energ[t + 1024];
    float m = waveMax(fmaxf(e0, e1));
    if (lane == 0) red[wid] = m;
    __syncthreads();
    float M = -1e30f;
    for (int q = 0; q < 16; ++q) M = fmaxf(M, red[q]);
    __syncthreads();
    float x0 = expf(e0 - M), x1 = expf(e1 - M);
    float s = waveSum(x0 + x1);
    if (lane == 0) red[wid] = s;
    __syncthreads();
    float S = 0.f;
    for (int q = 0; q < 16; ++q) S += red[q];
    attw[t] = x0 / S; attw[t + 1024] = x1 / S;
}

__global__ __launch_bounds__(256) void k_context(
        const float* __restrict__ enc, const float* __restrict__ attw,
        float* __restrict__ ctx) {
    const int k = (blockIdx.x & 3) * 256 + threadIdx.x;
    const int j0 = (blockIdx.x >> 2) * 64;
    float acc = 0.f;
#pragma unroll 8
    for (int j = j0; j < j0 + 64; ++j) acc += attw[j] * enc[(size_t)j * H + k];
    atomicAdd(&ctx[k], acc);
}

__global__ __launch_bounds__(256) void k_logits(
        const float* __restrict__ Wl, const float* __restrict__ vcat,
        const float* __restrict__ bl, float* __restrict__ logits) {
    const int wid = threadIdx.x >> 6, lane = threadIdx.x & 63;
    const int row = blockIdx.x * 4 + wid;
    const float* wr = Wl + (size_t)row * (2 * H);
    float acc = 0.f;
#pragma unroll
    for (int it = 0; it < 8; ++it) { int e = it*256 + lane*4; acc += dot4(ld4(wr+e), ld4(vcat+e)); }
    acc = waveSum(acc);
    if (lane == 0) logits[row] = acc + bl[row];
}

__global__ __launch_bounds__(1024) void k_logsoftmax(
        const float* __restrict__ logits, float* __restrict__ out) {
    const int t = threadIdx.x, wid = t >> 6, lane = t & 63;
    __shared__ float red[16];
    float m = -1e30f;
    for (int i = t; i < VOCAB; i += 1024) m = fmaxf(m, logits[i]);
    m = waveMax(m);
    if (lane == 0) red[wid] = m;
    __syncthreads();
    float M = -1e30f;
    for (int q = 0; q < 16; ++q) M = fmaxf(M, red[q]);
    __syncthreads();
    float s = 0.f;
    for (int i = t; i < VOCAB; i += 1024) s += expf(logits[i] - M);
    s = waveSum(s);
    if (lane == 0) red[wid] = s;
    __syncthreads();
    float S = 0.f;
    for (int q = 0; q < 16; ++q) S += red[q];
    const float lse = M + logf(S);
    for (int i = t; i < VOCAB; i += 1024) out[i] = logits[i] - lse;
}

extern "C" void kernel_launch(void* const* d_in, const int* in_sizes, int n_in,
                              void* d_out, int out_size, void* d_ws, size_t ws_size,
                              hipStream_t stream) {
    const int*   widx = (const int*)d_in[0];
    const float* lctx = (const float*)d_in[1];
    const float* h0   = (const float*)d_in[2];
    const float* enc  = (const float*)d_in[3];
    const float* emb  = (const float*)d_in[4];
    const float* W_ih = (const float*)d_in[5];
    const float* W_hh = (const float*)d_in[6];
    const float* b_ih = (const float*)d_in[7];
    const float* b_hh = (const float*)d_in[8];
    const float* Wa   = (const float*)d_in[9];
    // d_in[10] (ba): dropped — constant shift under softmax
    const float* Wl   = (const float*)d_in[11];
    const float* bl   = (const float*)d_in[12];
    float* out = (float*)d_out;
    float* ws  = (float*)d_ws;

    void* args[] = { (void*)&emb, (void*)&lctx, (void*)&h0, (void*)&W_ih,
                     (void*)&W_hh, (void*)&b_ih, (void*)&b_hh, (void*)&widx,
                     (void*)&enc, (void*)&Wa, (void*)&Wl, (void*)&bl,
                     (void*)&ws, (void*)&out };
    hipError_t err = hipLaunchCooperativeKernel((const void*)kfused, dim3(GRID),
                                                dim3(NTHR), args, 0, stream);
    if (err != hipSuccess) {
        // deterministic fallback: proven multi-kernel path
        float* h      = ws;
        float* ctx    = ws + 1024;
        float* u      = ws + 2048;
        float* energ  = ws + 3072;
        float* attw   = ws + 5120;
        float* logits = ws + 7168;
        k_lstm<<<1024, 256, 0, stream>>>(emb, lctx, h0, W_ih, W_hh, b_ih, b_hh, widx, h, u);
        k_wa<<<dim3(4, 32), 256, 0, stream>>>(Wa, h, u);
        k_energy<<<512, 256, 0, stream>>>(enc, u, energ);
        k_softmax<<<1, 1024, 0, stream>>>(energ, attw, ctx);
        k_context<<<128, 256, 0, stream>>>(enc, attw, ctx);
        k_logits<<<8000, 256, 0, stream>>>(Wl, ws /*vcat*/, bl, logits);
        k_logsoftmax<<<1, 1024, 0, stream>>>(logits, out);
    }
}